// Round 2
// baseline (613.376 us; speedup 1.0000x reference)
//
#include <hip/hip_runtime.h>
#include <hip/hip_bf16.h>

// AUGRU (DIEN) fused recurrent kernel. fp32 I/O, bf16 MFMA compute.
// B=2048, T=200, D=H=128. Each block owns BM=8 batch rows for the whole
// T loop (256 blocks = 1/CU); h state in fp32 LDS; weights in VGPRs as
// bf16 MFMA B-fragments. MFMA shape 16x16x32 (rows 8..15 zero-padded).

#define BB   2048
#define TT   200
#define DD   128
#define HH   128
#define NG   256     // 2H gate width
#define BM   8       // batch rows per block
#define KP   264     // xs row stride (shorts)
#define RHP  136     // rh row stride (shorts)
#define HP   132     // hs row stride (floats)
#define UP   132     // ubuf row stride (floats)
#define NTH  512

typedef __attribute__((ext_vector_type(8))) __bf16 bf16x8;
typedef __attribute__((ext_vector_type(4))) float  f32x4;

__device__ __forceinline__ unsigned short f2bf(float f) {
    union { float f; unsigned int i; } x; x.f = f;
    unsigned int r = (x.i + 0x7fffu + ((x.i >> 16) & 1u)) >> 16;
    return (unsigned short)r;
}
__device__ __forceinline__ __bf16 f2bfv(float f) {
    union { unsigned short u; __bf16 b; } c; c.u = f2bf(f); return c.b;
}

__global__ __launch_bounds__(NTH, 2)
void augru_kernel(const float* __restrict__ X,    // [B,T,D] fp32
                  const float* __restrict__ ATT,  // [B,T]   fp32
                  const int*   __restrict__ SL,   // [B]     i32
                  const float* __restrict__ WG,   // [256,256] fp32
                  const float* __restrict__ BG,   // [256]   fp32
                  const float* __restrict__ WC,   // [256,128] fp32
                  const float* __restrict__ BC,   // [128]   fp32
                  float*       __restrict__ OUT)  // [B,T,H] fp32
{
    __shared__ unsigned short xs[16 * KP];   // [16][264] bf16: cols 0..127=x_t, 128..255=h; rows 8..15 stay 0
    __shared__ unsigned short rh[16 * RHP];  // [16][136] bf16: r*h; rows 8..15 stay 0
    __shared__ float hs[BM * HP];            // fp32 h state
    __shared__ float ubuf[BM * UP];          // a_t * sigmoid(u)
    __shared__ float attall[BM * TT];        // all att scores for this block's rows
    __shared__ float biasg[NG];
    __shared__ float biasc[HH];
    __shared__ int   slbuf[BM];

    const int tid  = threadIdx.x;
    const int wave = tid >> 6;      // 0..7
    const int lane = tid & 63;
    const int quad = lane >> 4;     // 0..3
    const int l16  = lane & 15;
    const int b0   = blockIdx.x * BM;

    // ---------------- one-time init ----------------
    for (int i = tid; i < 16 * KP;  i += NTH) xs[i] = 0;
    for (int i = tid; i < 16 * RHP; i += NTH) rh[i] = 0;
    for (int i = tid; i < BM * HP;  i += NTH) hs[i] = 0.f;
    if (tid < NG)                 biasg[tid] = BG[tid];
    else if (tid < NG + HH)       biasc[tid - NG] = BC[tid - NG];
    else if (tid < NG + HH + BM)  slbuf[tid - NG - HH] = SL[b0 + tid - NG - HH];
    for (int tt2 = lane; tt2 < TT; tt2 += 64)
        attall[wave * TT + tt2] = ATT[(long)(b0 + wave) * TT + tt2];

    // Weight B-fragments (bf16) in registers.
    // B-frag (16x16x32): lane holds B[k = kk*32 + quad*8 + j][n = ntile*16 + l16]
    bf16x8 bgf[2][8];   // gate: cols [(2w)*16, (2w+2)*16)
    bf16x8 bcf[8];      // cand: cols [w*16, w*16+16)
    {
        const int ncol0 = (2 * wave) * 16 + l16;
        const int ncol1 = ncol0 + 16;
        const int nc    = wave * 16 + l16;
        #pragma unroll
        for (int kk = 0; kk < 8; ++kk) {
            bf16x8 t0, t1, t2;
            #pragma unroll
            for (int j = 0; j < 8; ++j) {
                const int k = kk * 32 + quad * 8 + j;
                t0[j] = f2bfv(WG[k * NG + ncol0]);
                t1[j] = f2bfv(WG[k * NG + ncol1]);
                t2[j] = f2bfv(WC[k * HH + nc]);
            }
            bgf[0][kk] = t0; bgf[1][kk] = t1; bcf[kk] = t2;
        }
    }
    __syncthreads();

    int tmax = 0;
    #pragma unroll
    for (int r = 0; r < BM; ++r) tmax = max(tmax, slbuf[r]);

    const int srow = tid >> 5;   // 0..7 (for tid < 256)
    const int sseg = tid & 31;   // 0..31

    float4 xpre;
    if (tid < 256 && tmax > 0)
        xpre = *(const float4*)&X[((long)(b0 + srow) * TT + 0) * DD + sseg * 4];

    // ---------------- time loop ----------------
    for (int t = 0; t < tmax; ++t) {
        if (tid < 256) {   // stage x_t (fp32 regs -> bf16 LDS)
            ushort4 v;
            v.x = f2bf(xpre.x); v.y = f2bf(xpre.y);
            v.z = f2bf(xpre.z); v.w = f2bf(xpre.w);
            *(ushort4*)&xs[srow * KP + sseg * 4] = v;
        }
        __syncthreads();   // SYNC A: x_t + h ready
        if (tid < 256 && t + 1 < tmax)   // prefetch t+1, overlaps whole step
            xpre = *(const float4*)&X[((long)(b0 + srow) * TT + (t + 1)) * DD + sseg * 4];

        // ---- gate GEMM: gi = [x|h] @ Wg  (K=256) ----
        f32x4 accg0 = {0.f,0.f,0.f,0.f}, accg1 = {0.f,0.f,0.f,0.f};
        #pragma unroll
        for (int kk = 0; kk < 8; ++kk) {
            const bf16x8 af = *(const bf16x8*)&xs[l16 * KP + kk * 32 + quad * 8];
            accg0 = __builtin_amdgcn_mfma_f32_16x16x32_bf16(af, bgf[0][kk], accg0, 0, 0, 0);
            accg1 = __builtin_amdgcn_mfma_f32_16x16x32_bf16(af, bgf[1][kk], accg1, 0, 0, 0);
        }
        if (quad < 2) {   // rows 0..7 valid; waves 0-3 -> r, waves 4-7 -> u
            #pragma unroll
            for (int nt2 = 0; nt2 < 2; ++nt2) {
                const f32x4 acc = nt2 ? accg1 : accg0;
                const int colg = (2 * wave + nt2) * 16 + l16;
                #pragma unroll
                for (int reg = 0; reg < 4; ++reg) {
                    const int row = quad * 4 + reg;
                    const float pre = acc[reg] + biasg[colg];
                    const float s = __builtin_amdgcn_rcpf(1.0f + __expf(-pre));
                    if (colg < HH) {
                        rh[row * RHP + colg] = f2bf(s * hs[row * HP + colg]);
                    } else {
                        ubuf[row * UP + (colg - HH)] = attall[row * TT + t] * s;
                    }
                }
            }
        }
        __syncthreads();   // SYNC B: rh, ubuf ready

        // ---- cand GEMM: c = [x | r*h] @ Wc  (K=256) ----
        f32x4 accc = {0.f,0.f,0.f,0.f};
        #pragma unroll
        for (int kk = 0; kk < 4; ++kk) {
            const bf16x8 af = *(const bf16x8*)&xs[l16 * KP + kk * 32 + quad * 8];
            accc = __builtin_amdgcn_mfma_f32_16x16x32_bf16(af, bcf[kk], accc, 0, 0, 0);
        }
        #pragma unroll
        for (int kk = 0; kk < 4; ++kk) {
            const bf16x8 af = *(const bf16x8*)&rh[l16 * RHP + kk * 32 + quad * 8];
            accc = __builtin_amdgcn_mfma_f32_16x16x32_bf16(af, bcf[kk + 4], accc, 0, 0, 0);
        }
        if (quad < 2) {   // update epilogue
            const int col = wave * 16 + l16;
            #pragma unroll
            for (int reg = 0; reg < 4; ++reg) {
                const int row = quad * 4 + reg;
                float xc = accc[reg] + biasc[col];
                xc = fminf(fmaxf(xc, -15.f), 15.f);
                const float e  = __expf(2.0f * xc);
                const float c  = (e - 1.0f) * __builtin_amdgcn_rcpf(e + 1.0f);
                const float u  = ubuf[row * UP + col];
                const float ho = hs[row * HP + col];
                const float nh = fmaf(u, c - ho, ho);
                const bool valid = t < slbuf[row];
                OUT[((long)(b0 + row) * TT + t) * HH + col] = valid ? nh : 0.f;
                if (valid) {
                    hs[row * HP + col] = nh;                 // fp32 carry
                    xs[row * KP + 128 + col] = f2bf(nh);     // bf16 for next MFMA
                }
            }
        }
        __syncthreads();   // SYNC C: before next x staging overwrites xs
    }

    // tail: outputs for t in [tmax, TT) are all zeros
    const int n4 = (TT - tmax) * (HH / 4);
    for (int r = 0; r < BM; ++r) {
        float4* p = (float4*)(OUT + ((long)(b0 + r) * TT + tmax) * HH);
        for (int i = tid; i < n4; i += NTH) p[i] = make_float4(0.f, 0.f, 0.f, 0.f);
    }
}

extern "C" void kernel_launch(void* const* d_in, const int* in_sizes, int n_in,
                              void* d_out, int out_size, void* d_ws, size_t ws_size,
                              hipStream_t stream) {
    (void)in_sizes; (void)n_in; (void)d_ws; (void)ws_size; (void)out_size;
    const float* X   = (const float*)d_in[0];
    const float* ATT = (const float*)d_in[1];
    const int*   SL  = (const int*)d_in[2];
    const float* WG  = (const float*)d_in[3];
    const float* BG  = (const float*)d_in[4];
    const float* WC  = (const float*)d_in[5];
    const float* BC  = (const float*)d_in[6];
    float*       OUT = (float*)d_out;
    hipLaunchKernelGGL(augru_kernel, dim3(BB / BM), dim3(NTH), 0, stream,
                       X, ATT, SL, WG, BG, WC, BC, OUT);
}

// Round 3
// 593.096 us; speedup vs baseline: 1.0342x; 1.0342x over previous
//
#include <hip/hip_runtime.h>
#include <hip/hip_bf16.h>

// AUGRU (DIEN) fused recurrent kernel. fp32 I/O, bf16 MFMA compute.
// B=2048, T=200, D=H=128. Block = 8 batch rows (256 blocks, 1/CU), 512 thr.
// Round 3: 2 barriers/step (double-buffered x), full-lane epilogues via
// __shfl_xor(32) redistribution, 4-way MFMA ILP, register biases.

#define BB   2048
#define TT   200
#define DD   128
#define HH   128
#define NG   256
#define BM   8
#define SB   136     // bf16 tile row stride (shorts): 68 dwords = 4 mod 32
#define SF   132     // fp32 row stride (floats)
#define NTH  512

typedef __attribute__((ext_vector_type(8))) __bf16 bf16x8;
typedef __attribute__((ext_vector_type(4))) float  f32x4;

#define MFMA(a, b, c) __builtin_amdgcn_mfma_f32_16x16x32_bf16((a), (b), (c), 0, 0, 0)

union bfu { __bf16 b; unsigned short u; };
__device__ __forceinline__ unsigned short f2bf(float f) { bfu c; c.b = (__bf16)f; return c.u; }
__device__ __forceinline__ __bf16 f2bfv(float f) { return (__bf16)f; }

__global__ __launch_bounds__(NTH, 2)
void augru_kernel(const float* __restrict__ X,    // [B,T,D]
                  const float* __restrict__ ATT,  // [B,T]
                  const int*   __restrict__ SL,   // [B]
                  const float* __restrict__ WG,   // [256,256]
                  const float* __restrict__ BG,   // [256]
                  const float* __restrict__ WC,   // [256,128]
                  const float* __restrict__ BC,   // [128]
                  float*       __restrict__ OUT)  // [B,T,H]
{
    __shared__ unsigned short xb[2][16 * SB];  // x_t double buffer, bf16, rows 8..15 = 0
    __shared__ unsigned short hb[16 * SB];     // h bf16 (A-frag source), rows 8..15 = 0
    __shared__ unsigned short rh[16 * SB];     // r*h bf16, rows 8..15 = 0
    __shared__ float hs[BM * SF];              // fp32 h master
    __shared__ float ub[BM * SF];              // a_t * sigmoid(u)
    __shared__ float attall[BM * TT];
    __shared__ int   slbuf[BM];

    const int tid  = threadIdx.x;
    const int wave = tid >> 6;
    const int lane = tid & 63;
    const int quad = lane >> 4;
    const int l16  = lane & 15;
    const int b0   = blockIdx.x * BM;
    const int qq   = quad & 1;       // row-group select after redistribution
    const int top  = quad >> 1;
    const int r0   = 4 * qq + 2 * top;   // this lane handles rows r0, r0+1

    // ---------------- one-time init ----------------
    for (int i = tid; i < 2 * 16 * SB; i += NTH) xb[0][i] = 0;   // both buffers
    for (int i = tid; i < 16 * SB; i += NTH) hb[i] = 0;
    for (int i = tid; i < 16 * SB; i += NTH) rh[i] = 0;
    for (int i = tid; i < BM * SF; i += NTH) { hs[i] = 0.f; ub[i] = 0.f; }
    for (int i = tid; i < BM * TT; i += NTH) attall[i] = ATT[(long)b0 * TT + i];
    if (tid < BM) slbuf[tid] = SL[b0 + tid];

    // per-lane biases (fixed columns per lane across all steps)
    const float bgv0 = BG[(2 * wave) * 16 + l16];
    const float bgv1 = BG[(2 * wave + 1) * 16 + l16];
    const float bcv  = BC[wave * 16 + l16];

    // Weight B-fragments (bf16) in registers.
    // B-frag (16x16x32): lane holds B[k = kk*32 + quad*8 + j][n = ntile*16 + l16]
    bf16x8 bgf[2][8], bcf[8];
    {
        const int nc0 = (2 * wave) * 16 + l16;
        const int nc1 = nc0 + 16;
        const int ncc = wave * 16 + l16;
        #pragma unroll
        for (int kk = 0; kk < 8; ++kk) {
            bf16x8 t0, t1, t2;
            #pragma unroll
            for (int j = 0; j < 8; ++j) {
                const int k = kk * 32 + quad * 8 + j;
                t0[j] = f2bfv(WG[k * NG + nc0]);
                t1[j] = f2bfv(WG[k * NG + nc1]);
                t2[j] = f2bfv(WC[k * HH + ncc]);
            }
            bgf[0][kk] = t0; bgf[1][kk] = t1; bcf[kk] = t2;
        }
    }
    __syncthreads();

    int tmax = 0;
    #pragma unroll
    for (int r = 0; r < BM; ++r) tmax = max(tmax, slbuf[r]);
    const int sl0 = slbuf[r0], sl1 = slbuf[r0 + 1];

    const int srow = tid >> 5;   // 0..7 for tid<256
    const int sseg = tid & 31;

    // prologue: stage x(0), prefetch x(1)
    float4 xpre;
    if (tid < 256 && tmax > 0) {
        xpre = *(const float4*)&X[((long)(b0 + srow) * TT + 0) * DD + sseg * 4];
        ushort4 v; v.x = f2bf(xpre.x); v.y = f2bf(xpre.y); v.z = f2bf(xpre.z); v.w = f2bf(xpre.w);
        *(ushort4*)&xb[0][srow * SB + sseg * 4] = v;
        if (tmax > 1)
            xpre = *(const float4*)&X[((long)(b0 + srow) * TT + 1) * DD + sseg * 4];
    }
    __syncthreads();   // SYNC A for t=0

    // ---------------- time loop ----------------
    for (int t = 0; t < tmax; ++t) {
        const unsigned short* xc = &xb[t & 1][0];

        // ---- gate GEMM: [x|h] @ Wg, 4 independent MFMA chains ----
        f32x4 a0 = {0.f,0.f,0.f,0.f}, a1 = {0.f,0.f,0.f,0.f};
        f32x4 a2 = {0.f,0.f,0.f,0.f}, a3 = {0.f,0.f,0.f,0.f};
        #pragma unroll
        for (int kk = 0; kk < 4; kk += 2) {
            const bf16x8 af0 = *(const bf16x8*)&xc[l16 * SB + kk * 32 + quad * 8];
            const bf16x8 af1 = *(const bf16x8*)&xc[l16 * SB + (kk + 1) * 32 + quad * 8];
            a0 = MFMA(af0, bgf[0][kk], a0);     a1 = MFMA(af0, bgf[1][kk], a1);
            a2 = MFMA(af1, bgf[0][kk + 1], a2); a3 = MFMA(af1, bgf[1][kk + 1], a3);
        }
        #pragma unroll
        for (int kk = 4; kk < 8; kk += 2) {
            const bf16x8 af0 = *(const bf16x8*)&hb[l16 * SB + (kk - 4) * 32 + quad * 8];
            const bf16x8 af1 = *(const bf16x8*)&hb[l16 * SB + (kk - 3) * 32 + quad * 8];
            a0 = MFMA(af0, bgf[0][kk], a0);     a1 = MFMA(af0, bgf[1][kk], a1);
            a2 = MFMA(af1, bgf[0][kk + 1], a2); a3 = MFMA(af1, bgf[1][kk + 1], a3);
        }

        // stage x(t+1) into the other buffer; then prefetch x(t+2)
        if (tid < 256 && t + 1 < tmax) {
            ushort4 v; v.x = f2bf(xpre.x); v.y = f2bf(xpre.y); v.z = f2bf(xpre.z); v.w = f2bf(xpre.w);
            *(ushort4*)&xb[(t + 1) & 1][srow * SB + sseg * 4] = v;
            if (t + 2 < tmax)
                xpre = *(const float4*)&X[((long)(b0 + srow) * TT + (t + 2)) * DD + sseg * 4];
        }

        // ---- gate epilogue (full-lane via xor-32 redistribution) ----
        const f32x4 g0 = a0 + a2;   // ntile 0
        const f32x4 g1 = a1 + a3;   // ntile 1
        float s20 = __shfl_xor(g0[2], 32, 64), s30 = __shfl_xor(g0[3], 32, 64);
        float s21 = __shfl_xor(g1[2], 32, 64), s31 = __shfl_xor(g1[3], 32, 64);
        #pragma unroll
        for (int nt = 0; nt < 2; ++nt) {
            const int colg = (2 * wave + nt) * 16 + l16;
            const float bg = nt ? bgv1 : bgv0;
            const float v0 = top ? (nt ? s21 : s20) : (nt ? g1[0] : g0[0]);
            const float v1 = top ? (nt ? s31 : s30) : (nt ? g1[1] : g0[1]);
            #pragma unroll
            for (int rr = 0; rr < 2; ++rr) {
                const int row = r0 + rr;
                const float pre = (rr ? v1 : v0) + bg;
                const float s = __builtin_amdgcn_rcpf(1.0f + __expf(-pre));
                if (wave < 4) {
                    rh[row * SB + colg] = f2bf(s * hs[row * SF + colg]);
                } else {
                    ub[row * SF + (colg - HH)] = attall[row * TT + t] * s;
                }
            }
        }
        __syncthreads();   // SYNC B: rh, ub ready

        // ---- cand GEMM: [x | r*h] @ Wc, 2 independent chains ----
        f32x4 c0 = {0.f,0.f,0.f,0.f}, c1 = {0.f,0.f,0.f,0.f};
        #pragma unroll
        for (int kk = 0; kk < 4; ++kk) {
            const bf16x8 afx = *(const bf16x8*)&xc[l16 * SB + kk * 32 + quad * 8];
            const bf16x8 afr = *(const bf16x8*)&rh[l16 * SB + kk * 32 + quad * 8];
            c0 = MFMA(afx, bcf[kk], c0);
            c1 = MFMA(afr, bcf[kk + 4], c1);
        }
        const f32x4 cc = c0 + c1;
        float t2 = __shfl_xor(cc[2], 32, 64), t3 = __shfl_xor(cc[3], 32, 64);

        // ---- update epilogue (full-lane) ----
        {
            const int col = wave * 16 + l16;
            const float w0 = top ? t2 : cc[0];
            const float w1 = top ? t3 : cc[1];
            #pragma unroll
            for (int rr = 0; rr < 2; ++rr) {
                const int row = r0 + rr;
                const float xv = (rr ? w1 : w0) + bcv;
                const float e  = __expf(2.0f * xv);
                const float c  = 1.0f - 2.0f * __builtin_amdgcn_rcpf(e + 1.0f);
                const float u  = ub[row * SF + col];
                const float ho = hs[row * SF + col];
                const float nh = fmaf(u, c - ho, ho);
                const bool valid = t < (rr ? sl1 : sl0);
                const float hst = valid ? nh : ho;
                hs[row * SF + col] = hst;
                hb[row * SB + col] = f2bf(hst);
                OUT[((long)(b0 + row) * TT + t) * HH + col] = valid ? nh : 0.f;
            }
        }
        __syncthreads();   // SYNC A for t+1: h (and staged x) ready
    }

    // tail: outputs for t in [tmax, TT) are zeros
    const int n4 = (TT - tmax) * (HH / 4);
    for (int r = 0; r < BM; ++r) {
        float4* p = (float4*)(OUT + ((long)(b0 + r) * TT + tmax) * HH);
        for (int i = tid; i < n4; i += NTH) p[i] = make_float4(0.f, 0.f, 0.f, 0.f);
    }
}

extern "C" void kernel_launch(void* const* d_in, const int* in_sizes, int n_in,
                              void* d_out, int out_size, void* d_ws, size_t ws_size,
                              hipStream_t stream) {
    (void)in_sizes; (void)n_in; (void)d_ws; (void)ws_size; (void)out_size;
    const float* X   = (const float*)d_in[0];
    const float* ATT = (const float*)d_in[1];
    const int*   SL  = (const int*)d_in[2];
    const float* WG  = (const float*)d_in[3];
    const float* BG  = (const float*)d_in[4];
    const float* WC  = (const float*)d_in[5];
    const float* BC  = (const float*)d_in[6];
    float*       OUT = (float*)d_out;
    hipLaunchKernelGGL(augru_kernel, dim3(BB / BM), dim3(NTH), 0, stream,
                       X, ATT, SL, WG, BG, WC, BC, OUT);
}